// Round 2
// baseline (409.082 us; speedup 1.0000x reference)
//
#include <hip/hip_runtime.h>
#include <cstdint>
#include <cstddef>

#define D_MODEL 2048
#define T_SEQ   2048
#define BATCH   2
#define N_HEADS 16
#define KV_HEADS 4
#define HEAD_DIM 128
#define QKV_N   3072          // D_MODEL + 2*512
#define ROWS    (BATCH * T_SEQ) // 4096

typedef float  floatx4 __attribute__((ext_vector_type(4)));
typedef short  shortx8 __attribute__((ext_vector_type(8)));
typedef __bf16 bf16x8  __attribute__((ext_vector_type(8)));

typedef const void __attribute__((address_space(1))) gvoid_t;
typedef void __attribute__((address_space(3)))       svoid_t;

__device__ __forceinline__ floatx4 mfma16(shortx8 a, shortx8 b, floatx4 c) {
  return __builtin_amdgcn_mfma_f32_16x16x32_bf16(
      __builtin_bit_cast(bf16x8, a), __builtin_bit_cast(bf16x8, b), c, 0, 0, 0);
}

__device__ __forceinline__ unsigned short f2bf(float f) {
  union { float f; unsigned int u; } v; v.f = f;
  unsigned int u = v.u;
  u += 0x7fffu + ((u >> 16) & 1u);   // RNE
  return (unsigned short)(u >> 16);
}

// native RNE cast — compiler emits v_cvt_pk_bf16_f32 for pairs (hot paths)
__device__ __forceinline__ unsigned short f2bf_hw(float f) {
  return __builtin_bit_cast(unsigned short, (__bf16)f);
}

// ---------------- fp32 -> bf16 elementwise (x) ----------------
__global__ void cvt_x(const float* __restrict__ in, unsigned short* __restrict__ out, int n4) {
  int i = blockIdx.x * blockDim.x + threadIdx.x;
  if (i >= n4) return;
  float4 v = ((const float4*)in)[i];
  ushort4 o;
  o.x = f2bf(v.x); o.y = f2bf(v.y); o.z = f2bf(v.z); o.w = f2bf(v.w);
  ((ushort4*)out)[i] = o;
}

// ---------------- fp32 W[K][N] -> bf16 Wt[N][K] ----------------
__global__ void transpose_cvt(const float* __restrict__ W, unsigned short* __restrict__ Wt,
                              int K, int N) {
  __shared__ float tile[32][33];
  int n0 = blockIdx.x * 32, k0 = blockIdx.y * 32;
  int tx = threadIdx.x, ty = threadIdx.y;   // (32, 8)
  #pragma unroll
  for (int i = 0; i < 32; i += 8)
    tile[ty + i][tx] = W[(size_t)(k0 + ty + i) * N + n0 + tx];
  __syncthreads();
  #pragma unroll
  for (int i = 0; i < 32; i += 8)
    Wt[(size_t)(n0 + ty + i) * K + k0 + tx] = f2bf(tile[tx][ty + i]);
}

// ---------------- K slice of qkv -> k_staged [b][kvh][d8][t][8] ----------------
__global__ void build_kt(const unsigned short* __restrict__ qkv, unsigned short* __restrict__ kst) {
  int o = blockIdx.x * blockDim.x + threadIdx.x;   // (((b*4+kvh)*16+d8)*2048 + t)
  int t   = o & 2047;
  int d8  = (o >> 11) & 15;
  int kvh = (o >> 15) & 3;
  int b   = o >> 17;
  uint4 v = *(const uint4*)(qkv + (size_t)(b * T_SEQ + t) * QKV_N
                            + D_MODEL + kvh * HEAD_DIM + d8 * 8);
  *(uint4*)(kst + (size_t)o * 8) = v;
}

// ---------------- V slice of qkv -> v_staged [b][kvh][t8][d][8] ----------------
__global__ void build_vt(const unsigned short* __restrict__ qkv, unsigned short* __restrict__ vst) {
  int o = blockIdx.x * blockDim.x + threadIdx.x;   // (((b*4+kvh)*256+t8)*128 + d)
  int d   = o & 127;
  int t8  = (o >> 7) & 255;
  int kvh = (o >> 15) & 3;
  int b   = o >> 17;
  const unsigned short* src = qkv + (size_t)(b * T_SEQ + t8 * 8) * QKV_N
                              + D_MODEL + 512 + kvh * HEAD_DIM + d;
  union { unsigned short s[8]; uint4 v; } tmp;
  #pragma unroll
  for (int j = 0; j < 8; ++j) tmp.s[j] = src[(size_t)j * QKV_N];
  *(uint4*)(vst + (size_t)o * 8) = tmp.v;
}

// ---------------- 256x256 8-phase bf16 GEMM: C = A[M][K] * Bt[N][K]^T + bias ----
__global__ __launch_bounds__(512, 2) void gemm256(
    const unsigned short* __restrict__ A,
    const unsigned short* __restrict__ Bt,
    const float* __restrict__ bias,
    void* __restrict__ Cout,
    int M, int N, int K, int c_bf16)
{
  __shared__ __align__(16) unsigned short lds[65536];  // A: [0,32768), B: [32768,65536)
  const int tid  = threadIdx.x;
  const int wave = tid >> 6, lane = tid & 63;
  const int quad = lane >> 4, l16 = lane & 15;
  const int wr = wave >> 2, wc = wave & 3;        // 2 x 4 wave grid
  const int bm = blockIdx.y * 256, bn = blockIdx.x * 256;
  const int NT = K >> 6;                          // 64-wide K tiles

  const int r0 = tid >> 3;                        // row 0..63 (j=0); +64 for j=1
  const int cx = (tid & 7) ^ (r0 & 7);            // inverse swizzle of k-chunk
  const size_t K64 = (size_t)64 * K;              // 64 rows worth of elements
  const unsigned short* a_src = A  + (size_t)(bm + r0) * K + cx * 8;
  const unsigned short* b_src = Bt + (size_t)(bn + r0) * K + cx * 8;
  const int wOff = wave * 512;                    // wave-uniform LDS offset (elems)

  #define LDSA_(buf, half) (lds + (((buf) << 1) + (half)) * 8192)
  #define LDSB_(buf, half) (lds + 32768 + (((buf) << 1) + (half)) * 8192)
  #define KOFF(h, t) ((size_t)(h) * 128 * K + (size_t)(t) * 64)
  #define STAGE(srcbase, ldshalf, koff) do {                                          \
    __builtin_amdgcn_global_load_lds((gvoid_t*)((srcbase) + (koff)),                  \
        (svoid_t*)((ldshalf) + wOff), 16, 0, 0);                                      \
    __builtin_amdgcn_global_load_lds((gvoid_t*)((srcbase) + (koff) + K64),            \
        (svoid_t*)((ldshalf) + wOff + 4096), 16, 0, 0);                               \
  } while (0)

  const int rowA = (wr * 64 + l16) * 64;          // within half-tile, elems
  const int rowB = (wc * 32 + l16) * 64;
  const int xo0 = ((quad)     ^ (l16 & 7)) * 8;   // ks=0 chunk
  const int xo1 = ((4 + quad) ^ (l16 & 7)) * 8;   // ks=1 chunk

  floatx4 acc[8][4] = {};
  shortx8 Afr[4][2];
  shortx8 Bfr[4][2];

  STAGE(a_src, LDSA_(0, 0), KOFF(0, 0));
  STAGE(b_src, LDSB_(0, 0), KOFF(0, 0));
  STAGE(b_src, LDSB_(0, 1), KOFF(1, 0));
  STAGE(a_src, LDSA_(0, 1), KOFF(1, 0));
  if (NT > 1) {
    STAGE(a_src, LDSA_(1, 0), KOFF(0, 1));
    STAGE(b_src, LDSB_(1, 0), KOFF(0, 1));
    STAGE(b_src, LDSB_(1, 1), KOFF(1, 1));
  }

  for (int t = 0; t < NT; ++t) {
    const int buf = t & 1;
    unsigned short* sA0 = LDSA_(buf, 0);
    unsigned short* sA1 = LDSA_(buf, 1);
    unsigned short* sB0 = LDSB_(buf, 0);
    unsigned short* sB1 = LDSB_(buf, 1);

    // ---- phase 0: Q(0,0) ----
    if (t == NT - 1) asm volatile("s_waitcnt vmcnt(0)" ::: "memory");
    else             asm volatile("s_waitcnt vmcnt(6)" ::: "memory");
    __builtin_amdgcn_s_barrier();
    #pragma unroll
    for (int mi = 0; mi < 4; ++mi) {
      Afr[mi][0] = *(const shortx8*)(sA0 + rowA + mi * 1024 + xo0);
      Afr[mi][1] = *(const shortx8*)(sA0 + rowA + mi * 1024 + xo1);
    }
    #pragma unroll
    for (int ni = 0; ni < 2; ++ni) {
      Bfr[ni][0] = *(const shortx8*)(sB0 + rowB + ni * 1024 + xo0);
      Bfr[ni][1] = *(const shortx8*)(sB0 + rowB + ni * 1024 + xo1);
    }
    if (t + 1 < NT) STAGE(a_src, LDSA_(buf ^ 1, 1), KOFF(1, t + 1));
    asm volatile("s_waitcnt lgkmcnt(0)" ::: "memory");
    __builtin_amdgcn_s_setprio(1);
    #pragma unroll
    for (int ks = 0; ks < 2; ++ks)
      #pragma unroll
      for (int mi = 0; mi < 4; ++mi)
        #pragma unroll
        for (int ni = 0; ni < 2; ++ni)
          acc[mi][ni] = mfma16(Afr[mi][ks], Bfr[ni][ks], acc[mi][ni]);
    __builtin_amdgcn_s_setprio(0);
    __builtin_amdgcn_s_barrier();

    // ---- phase 1: Q(0,1) ----
    #pragma unroll
    for (int ni = 0; ni < 2; ++ni) {
      Bfr[2 + ni][0] = *(const shortx8*)(sB1 + rowB + ni * 1024 + xo0);
      Bfr[2 + ni][1] = *(const shortx8*)(sB1 + rowB + ni * 1024 + xo1);
    }
    if (t + 2 < NT) STAGE(a_src, LDSA_(buf, 0), KOFF(0, t + 2));
    __builtin_amdgcn_s_barrier();
    asm volatile("s_waitcnt lgkmcnt(0)" ::: "memory");
    __builtin_amdgcn_s_setprio(1);
    #pragma unroll
    for (int ks = 0; ks < 2; ++ks)
      #pragma unroll
      for (int mi = 0; mi < 4; ++mi)
        #pragma unroll
        for (int ni = 0; ni < 2; ++ni)
          acc[mi][2 + ni] = mfma16(Afr[mi][ks], Bfr[2 + ni][ks], acc[mi][2 + ni]);
    __builtin_amdgcn_s_setprio(0);
    __builtin_amdgcn_s_barrier();

    // ---- phase 2: Q(1,1) ----
    #pragma unroll
    for (int mi = 0; mi < 4; ++mi) {
      Afr[mi][0] = *(const shortx8*)(sA1 + rowA + mi * 1024 + xo0);
      Afr[mi][1] = *(const shortx8*)(sA1 + rowA + mi * 1024 + xo1);
    }
    if (t + 2 < NT) STAGE(b_src, LDSB_(buf, 0), KOFF(0, t + 2));
    __builtin_amdgcn_s_barrier();
    asm volatile("s_waitcnt lgkmcnt(0)" ::: "memory");
    __builtin_amdgcn_s_setprio(1);
    #pragma unroll
    for (int ks = 0; ks < 2; ++ks)
      #pragma unroll
      for (int mi = 0; mi < 4; ++mi)
        #pragma unroll
        for (int ni = 0; ni < 2; ++ni)
          acc[4 + mi][2 + ni] = mfma16(Afr[mi][ks], Bfr[2 + ni][ks], acc[4 + mi][2 + ni]);
    __builtin_amdgcn_s_setprio(0);
    __builtin_amdgcn_s_barrier();

    // ---- phase 3: Q(1,0) ----
    if (t + 2 < NT) STAGE(b_src, LDSB_(buf, 1), KOFF(1, t + 2));
    __builtin_amdgcn_s_barrier();
    __builtin_amdgcn_s_setprio(1);
    #pragma unroll
    for (int ks = 0; ks < 2; ++ks)
      #pragma unroll
      for (int mi = 0; mi < 4; ++mi)
        #pragma unroll
        for (int ni = 0; ni < 2; ++ni)
          acc[4 + mi][ni] = mfma16(Afr[mi][ks], Bfr[ni][ks], acc[4 + mi][ni]);
    __builtin_amdgcn_s_setprio(0);
    __builtin_amdgcn_s_barrier();
  }

  #pragma unroll
  for (int mi = 0; mi < 8; ++mi) {
    const int row = bm + (mi >> 2) * 128 + wr * 64 + (mi & 3) * 16 + quad * 4;
    #pragma unroll
    for (int ni = 0; ni < 4; ++ni) {
      const int col = bn + (ni >> 1) * 128 + wc * 32 + (ni & 1) * 16 + l16;
      const float bv = bias[col];
      #pragma unroll
      for (int r = 0; r < 4; ++r) {
        float v = acc[mi][ni][r] + bv;
        if (c_bf16)
          ((unsigned short*)Cout)[(size_t)(row + r) * N + col] = f2bf_hw(v);
        else
          ((float*)Cout)[(size_t)(row + r) * N + col] = v;
      }
    }
  }
  #undef LDSA_
  #undef LDSB_
  #undef KOFF
  #undef STAGE
}

// ---------------- flash attention, GQA, causal ----------------
// grid (32, N_HEADS, B) = 1024 blocks, one 64-row Q-tile each, qt = 31 - bx
// (longest-processing-time-first for the in-order dispatcher). LDS = 40 KB
// exactly -> 4 blocks/CU resident (16 waves/CU) for latency hiding.
__global__ __launch_bounds__(256) void attn_kernel(
    const unsigned short* __restrict__ qkv,   // (B*T, 3072) bf16 (for Q)
    const unsigned short* __restrict__ kst,   // [b][kvh][d8][t][8]
    const unsigned short* __restrict__ vst,   // [b][kvh][t8][d][8]
    unsigned short* __restrict__ aout)        // (B*T, D_MODEL) bf16
{
  __shared__ __align__(16) unsigned short sK[16 * 64 * 8];   // [d8][key][8]
  __shared__ __align__(16) unsigned short sV[8 * 128 * 8];   // [t8][d][8]
  __shared__ __align__(16) unsigned short sP[4][8 * 16 * 8]; // per-wave [k8][row][8]

  const int tid  = threadIdx.x;
  const int wave = tid >> 6, lane = tid & 63;
  const int quad = lane >> 4, l16 = lane & 15;
  const int head = blockIdx.y, b = blockIdx.z;
  const int kvh = head >> 2;
  const float cf = 0.08838834764831845f * 1.4426950408889634f;  // scale*log2e
  const float THR = 25.0f;  // defer-max threshold (raw S units): P <= 2^(25*cf) ~ 9.1

  const unsigned short* kbase = kst + (size_t)((b * KV_HEADS + kvh) * 16) * 2048 * 8;
  const unsigned short* vbase = vst + (size_t)((b * KV_HEADS + kvh) * 256) * 128 * 8;
  unsigned short* sPw = sP[wave];

  const int qt = 31 - blockIdx.x;
  const int q0 = qt * 64;

  // Q fragments straight to registers (A-layout: row=l16, k=ks*32+quad*8)
  shortx8 qf[4];
  {
    const unsigned short* qp = qkv + (size_t)(b * T_SEQ + q0 + wave * 16 + l16) * QKV_N
                               + head * HEAD_DIM + quad * 8;
    #pragma unroll
    for (int ks = 0; ks < 4; ++ks)
      qf[ks] = *(const shortx8*)(qp + ks * 32);
  }

  float m_i[4], l_i[4];
  #pragma unroll
  for (int r = 0; r < 4; ++r) { m_i[r] = -__builtin_inff(); l_i[r] = 0.f; }
  floatx4 o_acc[8] = {};

  for (int kt = 0; kt <= qt; ++kt) {
    const int kb = kt * 64;

    __syncthreads();   // A: all waves done reading the previous tile
    #pragma unroll
    for (int it = 0; it < 4; ++it) {
      const int c = it * 4 + wave;
      __builtin_amdgcn_global_load_lds(
          (gvoid_t*)(kbase + ((size_t)c * 2048 + kb) * 8 + lane * 8),
          (svoid_t*)(sK + c * 512), 16, 0, 0);
    }
    const unsigned short* vtile = vbase + (size_t)(kb >> 3) * 128 * 8;
    #pragma unroll
    for (int it = 0; it < 4; ++it) {
      const int c = it * 4 + wave;
      __builtin_amdgcn_global_load_lds(
          (gvoid_t*)(vtile + c * 512 + lane * 8),
          (svoid_t*)(sV + c * 512), 16, 0, 0);
    }
    __syncthreads();   // B: tile visible (vmcnt drained by syncthreads)

    // S = Q K^T for this wave's 16 rows x 64 keys
    floatx4 s[4] = {};
    #pragma unroll
    for (int ks = 0; ks < 4; ++ks) {
      #pragma unroll
      for (int ct = 0; ct < 4; ++ct) {
        shortx8 kf = *(const shortx8*)&sK[((ks * 4 + quad) * 64 + ct * 16 + l16) * 8];
        s[ct] = mfma16(qf[ks], kf, s[ct]);
      }
    }

    // causal mask only on the diagonal tile (wave-uniform branch)
    if (kt == qt) {
      const int qrow = q0 + wave * 16 + quad * 4;
      #pragma unroll
      for (int ct = 0; ct < 4; ++ct) {
        const int kcol = kb + ct * 16 + l16;
        #pragma unroll
        for (int r = 0; r < 4; ++r)
          if (kcol > qrow + r) s[ct][r] = -__builtin_inff();
      }
    }

    // tile max per row (16-lane reduce across l16)
    float mx[4];
    #pragma unroll
    for (int r = 0; r < 4; ++r) {
      float m = fmaxf(fmaxf(s[0][r], s[1][r]), fmaxf(s[2][r], s[3][r]));
      m = fmaxf(m, __shfl_xor(m, 1));
      m = fmaxf(m, __shfl_xor(m, 2));
      m = fmaxf(m, __shfl_xor(m, 4));
      m = fmaxf(m, __shfl_xor(m, 8));
      mx[r] = m;
    }

    // defer-max (T13): only update m / rescale when the max moved by > THR.
    // Online softmax stays exact for any stale m; P bounded by 2^(THR*cf).
    if (__ballot((mx[0] > m_i[0] + THR) || (mx[1] > m_i[1] + THR) ||
                 (mx[2] > m_i[2] + THR) || (mx[3] > m_i[3] + THR))) {
      float alpha_r[4];
      #pragma unroll
      for (int r = 0; r < 4; ++r) {
        const float newm = fmaxf(m_i[r], mx[r]);
        alpha_r[r] = exp2f((m_i[r] - newm) * cf);
        m_i[r] = newm;
        l_i[r] *= alpha_r[r];
      }
      #pragma unroll
      for (int nt = 0; nt < 8; ++nt)
        #pragma unroll
        for (int r = 0; r < 4; ++r) o_acc[nt][r] *= alpha_r[r];
    }

    // P = exp2((S - m)*cf); per-lane partial l
    #pragma unroll
    for (int r = 0; r < 4; ++r) {
      const float nmc = m_i[r] * cf;
      float p0 = exp2f(fmaf(s[0][r], cf, -nmc));
      float p1 = exp2f(fmaf(s[1][r], cf, -nmc));
      float p2 = exp2f(fmaf(s[2][r], cf, -nmc));
      float p3 = exp2f(fmaf(s[3][r], cf, -nmc));
      s[0][r] = p0; s[1][r] = p1; s[2][r] = p2; s[3][r] = p3;
      l_i[r] += (p0 + p1) + (p2 + p3);
    }

    // P: C-layout -> A-layout swizzled [k8][row][8], per-wave (no barrier)
    #pragma unroll
    for (int ct = 0; ct < 4; ++ct)
      #pragma unroll
      for (int r = 0; r < 4; ++r)
        sPw[((ct * 2 + (l16 >> 3)) * 16 + quad * 4 + r) * 8 + (l16 & 7)] = f2bf_hw(s[ct][r]);
    __asm__ __volatile__("s_waitcnt lgkmcnt(0)" ::: "memory");

    // O += P V
    #pragma unroll
    for (int ks = 0; ks < 2; ++ks) {
      shortx8 pf = *(const shortx8*)&sPw[((ks * 4 + quad) * 16 + l16) * 8];
      #pragma unroll
      for (int nt = 0; nt < 8; ++nt) {
        shortx8 vf = *(const shortx8*)&sV[((ks * 4 + quad) * 128 + nt * 16 + l16) * 8];
        o_acc[nt] = mfma16(pf, vf, o_acc[nt]);
      }
    }
  }

  // epilogue
  const int trow = q0 + wave * 16 + quad * 4;
  #pragma unroll
  for (int r = 0; r < 4; ++r) {
    float l = l_i[r];
    l += __shfl_xor(l, 1);
    l += __shfl_xor(l, 2);
    l += __shfl_xor(l, 4);
    l += __shfl_xor(l, 8);
    const float inv = 1.f / l;
    #pragma unroll
    for (int nt = 0; nt < 8; ++nt) {
      aout[(size_t)(b * T_SEQ + trow + r) * D_MODEL + head * HEAD_DIM + nt * 16 + l16] =
          f2bf_hw(o_acc[nt][r] * inv);
    }
  }
}

extern "C" void kernel_launch(void* const* d_in, const int* in_sizes, int n_in,
                              void* d_out, int out_size, void* d_ws, size_t ws_size,
                              hipStream_t stream) {
  const float* x      = (const float*)d_in[0];
  // d_in[1] = attn_mask (causal; unused)
  const float* qkv_w  = (const float*)d_in[2];
  const float* qkv_b  = (const float*)d_in[3];
  const float* proj_w = (const float*)d_in[4];
  const float* proj_b = (const float*)d_in[5];
  float* out = (float*)d_out;

  char* ws = (char*)d_ws;
  unsigned short* x_bf    = (unsigned short*)(ws);
  unsigned short* qkvw_t  = (unsigned short*)(ws + (size_t)16777216);
  unsigned short* projw_t = (unsigned short*)(ws + (size_t)29360128);
  unsigned short* qkvbuf  = (unsigned short*)(ws + (size_t)37748736);
  unsigned short* vstaged = (unsigned short*)(ws + (size_t)62914560);
  unsigned short* kstaged = qkvw_t;  // safe alias: qkvw_t dead after GEMM1
  unsigned short* attn_out = x_bf;   // safe alias: x_bf dead after GEMM1

  cvt_x<<<(ROWS * D_MODEL / 4 + 255) / 256, 256, 0, stream>>>(x, x_bf, ROWS * D_MODEL / 4);
  transpose_cvt<<<dim3(QKV_N / 32, D_MODEL / 32), dim3(32, 8), 0, stream>>>(qkv_w, qkvw_t, D_MODEL, QKV_N);
  transpose_cvt<<<dim3(D_MODEL / 32, D_MODEL / 32), dim3(32, 8), 0, stream>>>(proj_w, projw_t, D_MODEL, D_MODEL);
  gemm256<<<dim3(QKV_N / 256, ROWS / 256), 512, 0, stream>>>(
      x_bf, qkvw_t, qkv_b, (void*)qkvbuf, ROWS, QKV_N, D_MODEL, 1);
  build_kt<<<1024, 256, 0, stream>>>(qkvbuf, kstaged);
  build_vt<<<1024, 256, 0, stream>>>(qkvbuf, vstaged);
  attn_kernel<<<dim3(32, N_HEADS, BATCH), 256, 0, stream>>>(qkvbuf, kstaged, vstaged, attn_out);
  gemm256<<<dim3(D_MODEL / 256, ROWS / 256), 512, 0, stream>>>(
      attn_out, projw_t, proj_b, (void*)out, ROWS, D_MODEL, D_MODEL, 0);
}

// Round 3
// 341.117 us; speedup vs baseline: 1.1992x; 1.1992x over previous
//
#include <hip/hip_runtime.h>
#include <cstdint>
#include <cstddef>

#define D_MODEL 2048
#define T_SEQ   2048
#define BATCH   2
#define N_HEADS 16
#define KV_HEADS 4
#define HEAD_DIM 128
#define QKV_N   3072          // D_MODEL + 2*512
#define ROWS    (BATCH * T_SEQ) // 4096

typedef float  floatx4 __attribute__((ext_vector_type(4)));
typedef short  shortx8 __attribute__((ext_vector_type(8)));
typedef __bf16 bf16x8  __attribute__((ext_vector_type(8)));

typedef const void __attribute__((address_space(1))) gvoid_t;
typedef void __attribute__((address_space(3)))       svoid_t;

__device__ __forceinline__ floatx4 mfma16(shortx8 a, shortx8 b, floatx4 c) {
  return __builtin_amdgcn_mfma_f32_16x16x32_bf16(
      __builtin_bit_cast(bf16x8, a), __builtin_bit_cast(bf16x8, b), c, 0, 0, 0);
}

__device__ __forceinline__ unsigned short f2bf(float f) {
  union { float f; unsigned int u; } v; v.f = f;
  unsigned int u = v.u;
  u += 0x7fffu + ((u >> 16) & 1u);   // RNE
  return (unsigned short)(u >> 16);
}

// native RNE cast — compiler emits v_cvt_pk_bf16_f32 for pairs (hot paths)
__device__ __forceinline__ unsigned short f2bf_hw(float f) {
  return __builtin_bit_cast(unsigned short, (__bf16)f);
}

// ---------------- fp32 -> bf16 elementwise (x) ----------------
__global__ void cvt_x(const float* __restrict__ in, unsigned short* __restrict__ out, int n4) {
  int i = blockIdx.x * blockDim.x + threadIdx.x;
  if (i >= n4) return;
  float4 v = ((const float4*)in)[i];
  ushort4 o;
  o.x = f2bf(v.x); o.y = f2bf(v.y); o.z = f2bf(v.z); o.w = f2bf(v.w);
  ((ushort4*)out)[i] = o;
}

// ---------------- fp32 W[K][N] -> bf16 Wt[N][K] ----------------
__global__ void transpose_cvt(const float* __restrict__ W, unsigned short* __restrict__ Wt,
                              int K, int N) {
  __shared__ float tile[32][33];
  int n0 = blockIdx.x * 32, k0 = blockIdx.y * 32;
  int tx = threadIdx.x, ty = threadIdx.y;   // (32, 8)
  #pragma unroll
  for (int i = 0; i < 32; i += 8)
    tile[ty + i][tx] = W[(size_t)(k0 + ty + i) * N + n0 + tx];
  __syncthreads();
  #pragma unroll
  for (int i = 0; i < 32; i += 8)
    Wt[(size_t)(n0 + ty + i) * K + k0 + tx] = f2bf(tile[tx][ty + i]);
}

// ---------------- K slice of qkv -> k_staged [b][kvh][d8][t][8] ----------------
__global__ void build_kt(const unsigned short* __restrict__ qkv, unsigned short* __restrict__ kst) {
  int o = blockIdx.x * blockDim.x + threadIdx.x;   // (((b*4+kvh)*16+d8)*2048 + t)
  int t   = o & 2047;
  int d8  = (o >> 11) & 15;
  int kvh = (o >> 15) & 3;
  int b   = o >> 17;
  uint4 v = *(const uint4*)(qkv + (size_t)(b * T_SEQ + t) * QKV_N
                            + D_MODEL + kvh * HEAD_DIM + d8 * 8);
  *(uint4*)(kst + (size_t)o * 8) = v;
}

// ---------------- V slice of qkv -> v_staged [b][kvh][t8][d][8] ----------------
__global__ void build_vt(const unsigned short* __restrict__ qkv, unsigned short* __restrict__ vst) {
  int o = blockIdx.x * blockDim.x + threadIdx.x;   // (((b*4+kvh)*256+t8)*128 + d)
  int d   = o & 127;
  int t8  = (o >> 7) & 255;
  int kvh = (o >> 15) & 3;
  int b   = o >> 17;
  const unsigned short* src = qkv + (size_t)(b * T_SEQ + t8 * 8) * QKV_N
                              + D_MODEL + 512 + kvh * HEAD_DIM + d;
  union { unsigned short s[8]; uint4 v; } tmp;
  #pragma unroll
  for (int j = 0; j < 8; ++j) tmp.s[j] = src[(size_t)j * QKV_N];
  *(uint4*)(vst + (size_t)o * 8) = tmp.v;
}

// ---------------- 256x256 8-phase bf16 GEMM: C = A[M][K] * Bt[N][K]^T + bias ----
__global__ __launch_bounds__(512, 2) void gemm256(
    const unsigned short* __restrict__ A,
    const unsigned short* __restrict__ Bt,
    const float* __restrict__ bias,
    void* __restrict__ Cout,
    int M, int N, int K, int c_bf16)
{
  __shared__ __align__(16) unsigned short lds[65536];  // A: [0,32768), B: [32768,65536)
  const int tid  = threadIdx.x;
  const int wave = tid >> 6, lane = tid & 63;
  const int quad = lane >> 4, l16 = lane & 15;
  const int wr = wave >> 2, wc = wave & 3;        // 2 x 4 wave grid
  const int bm = blockIdx.y * 256, bn = blockIdx.x * 256;
  const int NT = K >> 6;                          // 64-wide K tiles

  const int r0 = tid >> 3;                        // row 0..63 (j=0); +64 for j=1
  const int cx = (tid & 7) ^ (r0 & 7);            // inverse swizzle of k-chunk
  const size_t K64 = (size_t)64 * K;              // 64 rows worth of elements
  const unsigned short* a_src = A  + (size_t)(bm + r0) * K + cx * 8;
  const unsigned short* b_src = Bt + (size_t)(bn + r0) * K + cx * 8;
  const int wOff = wave * 512;                    // wave-uniform LDS offset (elems)

  #define LDSA_(buf, half) (lds + (((buf) << 1) + (half)) * 8192)
  #define LDSB_(buf, half) (lds + 32768 + (((buf) << 1) + (half)) * 8192)
  #define KOFF(h, t) ((size_t)(h) * 128 * K + (size_t)(t) * 64)
  #define STAGE(srcbase, ldshalf, koff) do {                                          \
    __builtin_amdgcn_global_load_lds((gvoid_t*)((srcbase) + (koff)),                  \
        (svoid_t*)((ldshalf) + wOff), 16, 0, 0);                                      \
    __builtin_amdgcn_global_load_lds((gvoid_t*)((srcbase) + (koff) + K64),            \
        (svoid_t*)((ldshalf) + wOff + 4096), 16, 0, 0);                               \
  } while (0)

  const int rowA = (wr * 64 + l16) * 64;          // within half-tile, elems
  const int rowB = (wc * 32 + l16) * 64;
  const int xo0 = ((quad)     ^ (l16 & 7)) * 8;   // ks=0 chunk
  const int xo1 = ((4 + quad) ^ (l16 & 7)) * 8;   // ks=1 chunk

  floatx4 acc[8][4] = {};
  shortx8 Afr[4][2];
  shortx8 Bfr[4][2];

  STAGE(a_src, LDSA_(0, 0), KOFF(0, 0));
  STAGE(b_src, LDSB_(0, 0), KOFF(0, 0));
  STAGE(b_src, LDSB_(0, 1), KOFF(1, 0));
  STAGE(a_src, LDSA_(0, 1), KOFF(1, 0));
  if (NT > 1) {
    STAGE(a_src, LDSA_(1, 0), KOFF(0, 1));
    STAGE(b_src, LDSB_(1, 0), KOFF(0, 1));
    STAGE(b_src, LDSB_(1, 1), KOFF(1, 1));
  }

  for (int t = 0; t < NT; ++t) {
    const int buf = t & 1;
    unsigned short* sA0 = LDSA_(buf, 0);
    unsigned short* sA1 = LDSA_(buf, 1);
    unsigned short* sB0 = LDSB_(buf, 0);
    unsigned short* sB1 = LDSB_(buf, 1);

    // ---- phase 0: Q(0,0) ----
    if (t == NT - 1) asm volatile("s_waitcnt vmcnt(0)" ::: "memory");
    else             asm volatile("s_waitcnt vmcnt(6)" ::: "memory");
    __builtin_amdgcn_s_barrier();
    #pragma unroll
    for (int mi = 0; mi < 4; ++mi) {
      Afr[mi][0] = *(const shortx8*)(sA0 + rowA + mi * 1024 + xo0);
      Afr[mi][1] = *(const shortx8*)(sA0 + rowA + mi * 1024 + xo1);
    }
    #pragma unroll
    for (int ni = 0; ni < 2; ++ni) {
      Bfr[ni][0] = *(const shortx8*)(sB0 + rowB + ni * 1024 + xo0);
      Bfr[ni][1] = *(const shortx8*)(sB0 + rowB + ni * 1024 + xo1);
    }
    if (t + 1 < NT) STAGE(a_src, LDSA_(buf ^ 1, 1), KOFF(1, t + 1));
    asm volatile("s_waitcnt lgkmcnt(0)" ::: "memory");
    __builtin_amdgcn_s_setprio(1);
    #pragma unroll
    for (int ks = 0; ks < 2; ++ks)
      #pragma unroll
      for (int mi = 0; mi < 4; ++mi)
        #pragma unroll
        for (int ni = 0; ni < 2; ++ni)
          acc[mi][ni] = mfma16(Afr[mi][ks], Bfr[ni][ks], acc[mi][ni]);
    __builtin_amdgcn_s_setprio(0);
    __builtin_amdgcn_s_barrier();

    // ---- phase 1: Q(0,1) ----
    #pragma unroll
    for (int ni = 0; ni < 2; ++ni) {
      Bfr[2 + ni][0] = *(const shortx8*)(sB1 + rowB + ni * 1024 + xo0);
      Bfr[2 + ni][1] = *(const shortx8*)(sB1 + rowB + ni * 1024 + xo1);
    }
    if (t + 2 < NT) STAGE(a_src, LDSA_(buf, 0), KOFF(0, t + 2));
    __builtin_amdgcn_s_barrier();
    asm volatile("s_waitcnt lgkmcnt(0)" ::: "memory");
    __builtin_amdgcn_s_setprio(1);
    #pragma unroll
    for (int ks = 0; ks < 2; ++ks)
      #pragma unroll
      for (int mi = 0; mi < 4; ++mi)
        #pragma unroll
        for (int ni = 0; ni < 2; ++ni)
          acc[mi][2 + ni] = mfma16(Afr[mi][ks], Bfr[2 + ni][ks], acc[mi][2 + ni]);
    __builtin_amdgcn_s_setprio(0);
    __builtin_amdgcn_s_barrier();

    // ---- phase 2: Q(1,1) ----
    #pragma unroll
    for (int mi = 0; mi < 4; ++mi) {
      Afr[mi][0] = *(const shortx8*)(sA1 + rowA + mi * 1024 + xo0);
      Afr[mi][1] = *(const shortx8*)(sA1 + rowA + mi * 1024 + xo1);
    }
    if (t + 2 < NT) STAGE(b_src, LDSB_(buf, 0), KOFF(0, t + 2));
    __builtin_amdgcn_s_barrier();
    asm volatile("s_waitcnt lgkmcnt(0)" ::: "memory");
    __builtin_amdgcn_s_setprio(1);
    #pragma unroll
    for (int ks = 0; ks < 2; ++ks)
      #pragma unroll
      for (int mi = 0; mi < 4; ++mi)
        #pragma unroll
        for (int ni = 0; ni < 2; ++ni)
          acc[4 + mi][2 + ni] = mfma16(Afr[mi][ks], Bfr[2 + ni][ks], acc[4 + mi][2 + ni]);
    __builtin_amdgcn_s_setprio(0);
    __builtin_amdgcn_s_barrier();

    // ---- phase 3: Q(1,0) ----
    if (t + 2 < NT) STAGE(b_src, LDSB_(buf, 1), KOFF(1, t + 2));
    __builtin_amdgcn_s_barrier();
    __builtin_amdgcn_s_setprio(1);
    #pragma unroll
    for (int ks = 0; ks < 2; ++ks)
      #pragma unroll
      for (int mi = 0; mi < 4; ++mi)
        #pragma unroll
        for (int ni = 0; ni < 2; ++ni)
          acc[4 + mi][ni] = mfma16(Afr[mi][ks], Bfr[ni][ks], acc[4 + mi][ni]);
    __builtin_amdgcn_s_setprio(0);
    __builtin_amdgcn_s_barrier();
  }

  #pragma unroll
  for (int mi = 0; mi < 8; ++mi) {
    const int row = bm + (mi >> 2) * 128 + wr * 64 + (mi & 3) * 16 + quad * 4;
    #pragma unroll
    for (int ni = 0; ni < 4; ++ni) {
      const int col = bn + (ni >> 1) * 128 + wc * 32 + (ni & 1) * 16 + l16;
      const float bv = bias[col];
      #pragma unroll
      for (int r = 0; r < 4; ++r) {
        float v = acc[mi][ni][r] + bv;
        if (c_bf16)
          ((unsigned short*)Cout)[(size_t)(row + r) * N + col] = f2bf_hw(v);
        else
          ((float*)Cout)[(size_t)(row + r) * N + col] = v;
      }
    }
  }
  #undef LDSA_
  #undef LDSB_
  #undef KOFF
  #undef STAGE
}

// ---------------- flash attention, GQA, causal — uniform-cost paired blocks ----
// grid (16, N_HEADS, B) = 512 blocks, each processing the Q-tile PAIR
// (31 - bx, bx): exactly 33 K-iterations per block -> zero tail, 2 blocks/CU.
// K/V double-buffered in LDS (72 KB total): prefetch tile kt+1 at top of
// iteration kt, wait vmcnt(8) (counted, never drained mid-loop), raw s_barrier
// + explicit lgkmcnt instead of __syncthreads (which would re-insert vmcnt(0)).
__global__ __launch_bounds__(256) void attn_kernel(
    const unsigned short* __restrict__ qkv,   // (B*T, 3072) bf16 (for Q)
    const unsigned short* __restrict__ kst,   // [b][kvh][d8][t][8]
    const unsigned short* __restrict__ vst,   // [b][kvh][t8][d][8]
    unsigned short* __restrict__ aout)        // (B*T, D_MODEL) bf16
{
  __shared__ __align__(16) unsigned short sK[2][16 * 64 * 8];   // [d8][key][8]
  __shared__ __align__(16) unsigned short sV[2][8 * 128 * 8];   // [t8][d][8]
  __shared__ __align__(16) unsigned short sP[4][8 * 16 * 8];    // per-wave [k8][row][8]

  const int tid  = threadIdx.x;
  const int wave = tid >> 6, lane = tid & 63;
  const int quad = lane >> 4, l16 = lane & 15;
  const int head = blockIdx.y, b = blockIdx.z;
  const int kvh = head >> 2;
  const float cf = 0.08838834764831845f * 1.4426950408889634f;  // scale*log2e
  const float THR = 25.0f;  // defer-max threshold (raw S units): P <= 2^(25*cf) ~ 9.1

  const unsigned short* kbase = kst + (size_t)((b * KV_HEADS + kvh) * 16) * 2048 * 8;
  const unsigned short* vbase = vst + (size_t)((b * KV_HEADS + kvh) * 256) * 128 * 8;
  unsigned short* sPw = sP[wave];

  // per-wave stage of one K/V tile into buffer `dst` (8 gload_lds / wave)
  #define STAGE_KV(dst, kb_) do {                                              \
    _Pragma("unroll")                                                          \
    for (int it_ = 0; it_ < 4; ++it_) {                                        \
      const int c_ = it_ * 4 + wave;                                           \
      __builtin_amdgcn_global_load_lds(                                        \
          (gvoid_t*)(kbase + ((size_t)c_ * 2048 + (kb_)) * 8 + lane * 8),      \
          (svoid_t*)(&sK[dst][c_ * 512]), 16, 0, 0);                           \
    }                                                                          \
    const unsigned short* vt_ = vbase + (size_t)((kb_) >> 3) * 128 * 8;        \
    _Pragma("unroll")                                                          \
    for (int it_ = 0; it_ < 4; ++it_) {                                        \
      const int c_ = it_ * 4 + wave;                                           \
      __builtin_amdgcn_global_load_lds(                                        \
          (gvoid_t*)(vt_ + c_ * 512 + lane * 8),                               \
          (svoid_t*)(&sV[dst][c_ * 512]), 16, 0, 0);                           \
    }                                                                          \
  } while (0)

  #pragma unroll 1
  for (int half = 0; half < 2; ++half) {
    const int qt = half ? blockIdx.x : (31 - blockIdx.x);
    const int q0 = qt * 64;

    // Q fragments straight to registers (A-layout: row=l16, k=ks*32+quad*8)
    shortx8 qf[4];
    {
      const unsigned short* qp = qkv + (size_t)(b * T_SEQ + q0 + wave * 16 + l16) * QKV_N
                                 + head * HEAD_DIM + quad * 8;
      #pragma unroll
      for (int ks = 0; ks < 4; ++ks)
        qf[ks] = *(const shortx8*)(qp + ks * 32);
    }

    float m_i[4], l_i[4];
    #pragma unroll
    for (int r = 0; r < 4; ++r) { m_i[r] = -__builtin_inff(); l_i[r] = 0.f; }
    floatx4 o_acc[8] = {};

    // prologue: stage tile 0 into buf 0 (prev half's reads ended with a barrier)
    STAGE_KV(0, 0);

    for (int kt = 0; kt <= qt; ++kt) {
      const int cur = kt & 1;
      const unsigned short* sKc = sK[cur];
      const unsigned short* sVc = sV[cur];

      // prefetch next tile into the other buffer, then wait only for tile kt
      if (kt < qt) {
        STAGE_KV(cur ^ 1, (kt + 1) * 64);
        asm volatile("s_waitcnt vmcnt(8)" ::: "memory");
      } else {
        asm volatile("s_waitcnt vmcnt(0)" ::: "memory");
      }
      __builtin_amdgcn_s_barrier();   // tile kt visible to all waves

      // S = Q K^T for this wave's 16 rows x 64 keys
      floatx4 s[4] = {};
      __builtin_amdgcn_s_setprio(1);
      #pragma unroll
      for (int ks = 0; ks < 4; ++ks) {
        #pragma unroll
        for (int ct = 0; ct < 4; ++ct) {
          shortx8 kf = *(const shortx8*)&sKc[((ks * 4 + quad) * 64 + ct * 16 + l16) * 8];
          s[ct] = mfma16(qf[ks], kf, s[ct]);
        }
      }
      __builtin_amdgcn_s_setprio(0);

      // causal mask only on the diagonal tile (wave-uniform branch)
      if (kt == qt) {
        const int qrow = q0 + wave * 16 + quad * 4;
        const int kb = kt * 64;
        #pragma unroll
        for (int ct = 0; ct < 4; ++ct) {
          const int kcol = kb + ct * 16 + l16;
          #pragma unroll
          for (int r = 0; r < 4; ++r)
            if (kcol > qrow + r) s[ct][r] = -__builtin_inff();
        }
      }

      // tile max per row (16-lane reduce across l16)
      float mx[4];
      #pragma unroll
      for (int r = 0; r < 4; ++r) {
        float m = fmaxf(fmaxf(s[0][r], s[1][r]), fmaxf(s[2][r], s[3][r]));
        m = fmaxf(m, __shfl_xor(m, 1));
        m = fmaxf(m, __shfl_xor(m, 2));
        m = fmaxf(m, __shfl_xor(m, 4));
        m = fmaxf(m, __shfl_xor(m, 8));
        mx[r] = m;
      }

      // defer-max (T13): only update m / rescale when the max moved by > THR.
      // Online softmax stays exact for any stale m; P bounded by 2^(THR*cf).
      if (__ballot((mx[0] > m_i[0] + THR) || (mx[1] > m_i[1] + THR) ||
                   (mx[2] > m_i[2] + THR) || (mx[3] > m_i[3] + THR))) {
        float alpha_r[4];
        #pragma unroll
        for (int r = 0; r < 4; ++r) {
          const float newm = fmaxf(m_i[r], mx[r]);
          alpha_r[r] = exp2f((m_i[r] - newm) * cf);
          m_i[r] = newm;
          l_i[r] *= alpha_r[r];
        }
        #pragma unroll
        for (int nt = 0; nt < 8; ++nt)
          #pragma unroll
          for (int r = 0; r < 4; ++r) o_acc[nt][r] *= alpha_r[r];
      }

      // P = exp2((S - m)*cf); per-lane partial l
      #pragma unroll
      for (int r = 0; r < 4; ++r) {
        const float nmc = m_i[r] * cf;
        float p0 = exp2f(fmaf(s[0][r], cf, -nmc));
        float p1 = exp2f(fmaf(s[1][r], cf, -nmc));
        float p2 = exp2f(fmaf(s[2][r], cf, -nmc));
        float p3 = exp2f(fmaf(s[3][r], cf, -nmc));
        s[0][r] = p0; s[1][r] = p1; s[2][r] = p2; s[3][r] = p3;
        l_i[r] += (p0 + p1) + (p2 + p3);
      }

      // P: C-layout -> A-layout swizzled [k8][row][8], per-wave (no barrier)
      #pragma unroll
      for (int ct = 0; ct < 4; ++ct)
        #pragma unroll
        for (int r = 0; r < 4; ++r)
          sPw[((ct * 2 + (l16 >> 3)) * 16 + quad * 4 + r) * 8 + (l16 & 7)] = f2bf_hw(s[ct][r]);
      __asm__ __volatile__("s_waitcnt lgkmcnt(0)" ::: "memory");

      // O += P V
      __builtin_amdgcn_s_setprio(1);
      #pragma unroll
      for (int ks = 0; ks < 2; ++ks) {
        shortx8 pf = *(const shortx8*)&sPw[((ks * 4 + quad) * 16 + l16) * 8];
        #pragma unroll
        for (int nt = 0; nt < 8; ++nt) {
          shortx8 vf = *(const shortx8*)&sVc[((ks * 4 + quad) * 128 + nt * 16 + l16) * 8];
          o_acc[nt] = mfma16(pf, vf, o_acc[nt]);
        }
      }
      __builtin_amdgcn_s_setprio(0);

      // all this wave's LDS reads complete, then barrier so next iteration's
      // stage can safely overwrite buffer cur
      asm volatile("s_waitcnt lgkmcnt(0)" ::: "memory");
      __builtin_amdgcn_s_barrier();
    }

    // epilogue for this q-tile
    const int trow = q0 + wave * 16 + quad * 4;
    #pragma unroll
    for (int r = 0; r < 4; ++r) {
      float l = l_i[r];
      l += __shfl_xor(l, 1);
      l += __shfl_xor(l, 2);
      l += __shfl_xor(l, 4);
      l += __shfl_xor(l, 8);
      const float inv = 1.f / l;
      #pragma unroll
      for (int nt = 0; nt < 8; ++nt) {
        aout[(size_t)(b * T_SEQ + trow + r) * D_MODEL + head * HEAD_DIM + nt * 16 + l16] =
            f2bf_hw(o_acc[nt][r] * inv);
      }
    }
  }
  #undef STAGE_KV
}

extern "C" void kernel_launch(void* const* d_in, const int* in_sizes, int n_in,
                              void* d_out, int out_size, void* d_ws, size_t ws_size,
                              hipStream_t stream) {
  const float* x      = (const float*)d_in[0];
  // d_in[1] = attn_mask (causal; unused)
  const float* qkv_w  = (const float*)d_in[2];
  const float* qkv_b  = (const float*)d_in[3];
  const float* proj_w = (const float*)d_in[4];
  const float* proj_b = (const float*)d_in[5];
  float* out = (float*)d_out;

  char* ws = (char*)d_ws;
  unsigned short* x_bf    = (unsigned short*)(ws);
  unsigned short* qkvw_t  = (unsigned short*)(ws + (size_t)16777216);
  unsigned short* projw_t = (unsigned short*)(ws + (size_t)29360128);
  unsigned short* qkvbuf  = (unsigned short*)(ws + (size_t)37748736);
  unsigned short* vstaged = (unsigned short*)(ws + (size_t)62914560);
  unsigned short* kstaged = qkvw_t;  // safe alias: qkvw_t dead after GEMM1
  unsigned short* attn_out = x_bf;   // safe alias: x_bf dead after GEMM1

  cvt_x<<<(ROWS * D_MODEL / 4 + 255) / 256, 256, 0, stream>>>(x, x_bf, ROWS * D_MODEL / 4);
  transpose_cvt<<<dim3(QKV_N / 32, D_MODEL / 32), dim3(32, 8), 0, stream>>>(qkv_w, qkvw_t, D_MODEL, QKV_N);
  transpose_cvt<<<dim3(D_MODEL / 32, D_MODEL / 32), dim3(32, 8), 0, stream>>>(proj_w, projw_t, D_MODEL, D_MODEL);
  gemm256<<<dim3(QKV_N / 256, ROWS / 256), 512, 0, stream>>>(
      x_bf, qkvw_t, qkv_b, (void*)qkvbuf, ROWS, QKV_N, D_MODEL, 1);
  build_kt<<<1024, 256, 0, stream>>>(qkvbuf, kstaged);
  build_vt<<<1024, 256, 0, stream>>>(qkvbuf, vstaged);
  attn_kernel<<<dim3(16, N_HEADS, BATCH), 256, 0, stream>>>(qkvbuf, kstaged, vstaged, attn_out);
  gemm256<<<dim3(D_MODEL / 256, ROWS / 256), 512, 0, stream>>>(
      attn_out, projw_t, proj_b, (void*)out, ROWS, D_MODEL, D_MODEL, 0);
}

// Round 4
// 329.605 us; speedup vs baseline: 1.2411x; 1.0349x over previous
//
#include <hip/hip_runtime.h>
#include <cstdint>
#include <cstddef>

#define D_MODEL 2048
#define T_SEQ   2048
#define BATCH   2
#define N_HEADS 16
#define KV_HEADS 4
#define HEAD_DIM 128
#define QKV_N   3072          // D_MODEL + 2*512
#define ROWS    (BATCH * T_SEQ) // 4096

typedef float  floatx4 __attribute__((ext_vector_type(4)));
typedef short  shortx8 __attribute__((ext_vector_type(8)));
typedef __bf16 bf16x8  __attribute__((ext_vector_type(8)));

typedef const void __attribute__((address_space(1))) gvoid_t;
typedef void __attribute__((address_space(3)))       svoid_t;

__device__ __forceinline__ floatx4 mfma16(shortx8 a, shortx8 b, floatx4 c) {
  return __builtin_amdgcn_mfma_f32_16x16x32_bf16(
      __builtin_bit_cast(bf16x8, a), __builtin_bit_cast(bf16x8, b), c, 0, 0, 0);
}

__device__ __forceinline__ unsigned short f2bf(float f) {
  union { float f; unsigned int u; } v; v.f = f;
  unsigned int u = v.u;
  u += 0x7fffu + ((u >> 16) & 1u);   // RNE
  return (unsigned short)(u >> 16);
}

// native RNE cast — compiler emits v_cvt_pk_bf16_f32 for pairs (hot paths)
__device__ __forceinline__ unsigned short f2bf_hw(float f) {
  return __builtin_bit_cast(unsigned short, (__bf16)f);
}

// ---------------- fp32 -> bf16 elementwise (x) ----------------
__global__ void cvt_x(const float* __restrict__ in, unsigned short* __restrict__ out, int n4) {
  int i = blockIdx.x * blockDim.x + threadIdx.x;
  if (i >= n4) return;
  float4 v = ((const float4*)in)[i];
  ushort4 o;
  o.x = f2bf(v.x); o.y = f2bf(v.y); o.z = f2bf(v.z); o.w = f2bf(v.w);
  ((ushort4*)out)[i] = o;
}

// ---------------- fp32 W[K][N] -> bf16 Wt[N][K] ----------------
__global__ void transpose_cvt(const float* __restrict__ W, unsigned short* __restrict__ Wt,
                              int K, int N) {
  __shared__ float tile[32][33];
  int n0 = blockIdx.x * 32, k0 = blockIdx.y * 32;
  int tx = threadIdx.x, ty = threadIdx.y;   // (32, 8)
  #pragma unroll
  for (int i = 0; i < 32; i += 8)
    tile[ty + i][tx] = W[(size_t)(k0 + ty + i) * N + n0 + tx];
  __syncthreads();
  #pragma unroll
  for (int i = 0; i < 32; i += 8)
    Wt[(size_t)(n0 + ty + i) * K + k0 + tx] = f2bf(tile[tx][ty + i]);
}

// ---------------- K slice of qkv -> k_staged [b][kvh][d8][t][8] ----------------
__global__ void build_kt(const unsigned short* __restrict__ qkv, unsigned short* __restrict__ kst) {
  int o = blockIdx.x * blockDim.x + threadIdx.x;   // (((b*4+kvh)*16+d8)*2048 + t)
  int t   = o & 2047;
  int d8  = (o >> 11) & 15;
  int kvh = (o >> 15) & 3;
  int b   = o >> 17;
  uint4 v = *(const uint4*)(qkv + (size_t)(b * T_SEQ + t) * QKV_N
                            + D_MODEL + kvh * HEAD_DIM + d8 * 8);
  *(uint4*)(kst + (size_t)o * 8) = v;
}

// ---------------- V slice of qkv -> v_staged [b][kvh][t8][d][8] ----------------
__global__ void build_vt(const unsigned short* __restrict__ qkv, unsigned short* __restrict__ vst) {
  int o = blockIdx.x * blockDim.x + threadIdx.x;   // (((b*4+kvh)*256+t8)*128 + d)
  int d   = o & 127;
  int t8  = (o >> 7) & 255;
  int kvh = (o >> 15) & 3;
  int b   = o >> 17;
  const unsigned short* src = qkv + (size_t)(b * T_SEQ + t8 * 8) * QKV_N
                              + D_MODEL + 512 + kvh * HEAD_DIM + d;
  union { unsigned short s[8]; uint4 v; } tmp;
  #pragma unroll
  for (int j = 0; j < 8; ++j) tmp.s[j] = src[(size_t)j * QKV_N];
  *(uint4*)(vst + (size_t)o * 8) = tmp.v;
}

// ---------------- 256x256 8-phase bf16 GEMM: C = A[M][K] * Bt[N][K]^T + bias ----
__global__ __launch_bounds__(512, 2) void gemm256(
    const unsigned short* __restrict__ A,
    const unsigned short* __restrict__ Bt,
    const float* __restrict__ bias,
    void* __restrict__ Cout,
    int M, int N, int K, int c_bf16)
{
  __shared__ __align__(16) unsigned short lds[65536];  // A: [0,32768), B: [32768,65536)
  const int tid  = threadIdx.x;
  const int wave = tid >> 6, lane = tid & 63;
  const int quad = lane >> 4, l16 = lane & 15;
  const int wr = wave >> 2, wc = wave & 3;        // 2 x 4 wave grid
  const int bm = blockIdx.y * 256, bn = blockIdx.x * 256;
  const int NT = K >> 6;                          // 64-wide K tiles

  const int r0 = tid >> 3;                        // row 0..63 (j=0); +64 for j=1
  const int cx = (tid & 7) ^ (r0 & 7);            // inverse swizzle of k-chunk
  const size_t K64 = (size_t)64 * K;              // 64 rows worth of elements
  const unsigned short* a_src = A  + (size_t)(bm + r0) * K + cx * 8;
  const unsigned short* b_src = Bt + (size_t)(bn + r0) * K + cx * 8;
  const int wOff = wave * 512;                    // wave-uniform LDS offset (elems)

  #define LDSA_(buf, half) (lds + (((buf) << 1) + (half)) * 8192)
  #define LDSB_(buf, half) (lds + 32768 + (((buf) << 1) + (half)) * 8192)
  #define KOFF(h, t) ((size_t)(h) * 128 * K + (size_t)(t) * 64)
  #define STAGE(srcbase, ldshalf, koff) do {                                          \
    __builtin_amdgcn_global_load_lds((gvoid_t*)((srcbase) + (koff)),                  \
        (svoid_t*)((ldshalf) + wOff), 16, 0, 0);                                      \
    __builtin_amdgcn_global_load_lds((gvoid_t*)((srcbase) + (koff) + K64),            \
        (svoid_t*)((ldshalf) + wOff + 4096), 16, 0, 0);                               \
  } while (0)

  const int rowA = (wr * 64 + l16) * 64;          // within half-tile, elems
  const int rowB = (wc * 32 + l16) * 64;
  const int xo0 = ((quad)     ^ (l16 & 7)) * 8;   // ks=0 chunk
  const int xo1 = ((4 + quad) ^ (l16 & 7)) * 8;   // ks=1 chunk

  floatx4 acc[8][4] = {};
  shortx8 Afr[4][2];
  shortx8 Bfr[4][2];

  STAGE(a_src, LDSA_(0, 0), KOFF(0, 0));
  STAGE(b_src, LDSB_(0, 0), KOFF(0, 0));
  STAGE(b_src, LDSB_(0, 1), KOFF(1, 0));
  STAGE(a_src, LDSA_(0, 1), KOFF(1, 0));
  if (NT > 1) {
    STAGE(a_src, LDSA_(1, 0), KOFF(0, 1));
    STAGE(b_src, LDSB_(1, 0), KOFF(0, 1));
    STAGE(b_src, LDSB_(1, 1), KOFF(1, 1));
  }

  for (int t = 0; t < NT; ++t) {
    const int buf = t & 1;
    unsigned short* sA0 = LDSA_(buf, 0);
    unsigned short* sA1 = LDSA_(buf, 1);
    unsigned short* sB0 = LDSB_(buf, 0);
    unsigned short* sB1 = LDSB_(buf, 1);

    // ---- phase 0: Q(0,0) ----
    if (t == NT - 1) asm volatile("s_waitcnt vmcnt(0)" ::: "memory");
    else             asm volatile("s_waitcnt vmcnt(6)" ::: "memory");
    __builtin_amdgcn_s_barrier();
    #pragma unroll
    for (int mi = 0; mi < 4; ++mi) {
      Afr[mi][0] = *(const shortx8*)(sA0 + rowA + mi * 1024 + xo0);
      Afr[mi][1] = *(const shortx8*)(sA0 + rowA + mi * 1024 + xo1);
    }
    #pragma unroll
    for (int ni = 0; ni < 2; ++ni) {
      Bfr[ni][0] = *(const shortx8*)(sB0 + rowB + ni * 1024 + xo0);
      Bfr[ni][1] = *(const shortx8*)(sB0 + rowB + ni * 1024 + xo1);
    }
    if (t + 1 < NT) STAGE(a_src, LDSA_(buf ^ 1, 1), KOFF(1, t + 1));
    asm volatile("s_waitcnt lgkmcnt(0)" ::: "memory");
    __builtin_amdgcn_s_setprio(1);
    #pragma unroll
    for (int ks = 0; ks < 2; ++ks)
      #pragma unroll
      for (int mi = 0; mi < 4; ++mi)
        #pragma unroll
        for (int ni = 0; ni < 2; ++ni)
          acc[mi][ni] = mfma16(Afr[mi][ks], Bfr[ni][ks], acc[mi][ni]);
    __builtin_amdgcn_s_setprio(0);
    __builtin_amdgcn_s_barrier();

    // ---- phase 1: Q(0,1) ----
    #pragma unroll
    for (int ni = 0; ni < 2; ++ni) {
      Bfr[2 + ni][0] = *(const shortx8*)(sB1 + rowB + ni * 1024 + xo0);
      Bfr[2 + ni][1] = *(const shortx8*)(sB1 + rowB + ni * 1024 + xo1);
    }
    if (t + 2 < NT) STAGE(a_src, LDSA_(buf, 0), KOFF(0, t + 2));
    __builtin_amdgcn_s_barrier();
    asm volatile("s_waitcnt lgkmcnt(0)" ::: "memory");
    __builtin_amdgcn_s_setprio(1);
    #pragma unroll
    for (int ks = 0; ks < 2; ++ks)
      #pragma unroll
      for (int mi = 0; mi < 4; ++mi)
        #pragma unroll
        for (int ni = 0; ni < 2; ++ni)
          acc[mi][2 + ni] = mfma16(Afr[mi][ks], Bfr[2 + ni][ks], acc[mi][2 + ni]);
    __builtin_amdgcn_s_setprio(0);
    __builtin_amdgcn_s_barrier();

    // ---- phase 2: Q(1,1) ----
    #pragma unroll
    for (int mi = 0; mi < 4; ++mi) {
      Afr[mi][0] = *(const shortx8*)(sA1 + rowA + mi * 1024 + xo0);
      Afr[mi][1] = *(const shortx8*)(sA1 + rowA + mi * 1024 + xo1);
    }
    if (t + 2 < NT) STAGE(b_src, LDSB_(buf, 0), KOFF(0, t + 2));
    __builtin_amdgcn_s_barrier();
    asm volatile("s_waitcnt lgkmcnt(0)" ::: "memory");
    __builtin_amdgcn_s_setprio(1);
    #pragma unroll
    for (int ks = 0; ks < 2; ++ks)
      #pragma unroll
      for (int mi = 0; mi < 4; ++mi)
        #pragma unroll
        for (int ni = 0; ni < 2; ++ni)
          acc[4 + mi][2 + ni] = mfma16(Afr[mi][ks], Bfr[2 + ni][ks], acc[4 + mi][2 + ni]);
    __builtin_amdgcn_s_setprio(0);
    __builtin_amdgcn_s_barrier();

    // ---- phase 3: Q(1,0) ----
    if (t + 2 < NT) STAGE(b_src, LDSB_(buf, 1), KOFF(1, t + 2));
    __builtin_amdgcn_s_barrier();
    __builtin_amdgcn_s_setprio(1);
    #pragma unroll
    for (int ks = 0; ks < 2; ++ks)
      #pragma unroll
      for (int mi = 0; mi < 4; ++mi)
        #pragma unroll
        for (int ni = 0; ni < 2; ++ni)
          acc[4 + mi][ni] = mfma16(Afr[mi][ks], Bfr[ni][ks], acc[4 + mi][ni]);
    __builtin_amdgcn_s_setprio(0);
    __builtin_amdgcn_s_barrier();
  }

  #pragma unroll
  for (int mi = 0; mi < 8; ++mi) {
    const int row = bm + (mi >> 2) * 128 + wr * 64 + (mi & 3) * 16 + quad * 4;
    #pragma unroll
    for (int ni = 0; ni < 4; ++ni) {
      const int col = bn + (ni >> 1) * 128 + wc * 32 + (ni & 1) * 16 + l16;
      const float bv = bias[col];
      #pragma unroll
      for (int r = 0; r < 4; ++r) {
        float v = acc[mi][ni][r] + bv;
        if (c_bf16)
          ((unsigned short*)Cout)[(size_t)(row + r) * N + col] = f2bf_hw(v);
        else
          ((float*)Cout)[(size_t)(row + r) * N + col] = v;
      }
    }
  }
  #undef LDSA_
  #undef LDSB_
  #undef KOFF
  #undef STAGE
}

// ---------------- flash attention, GQA, causal — paired blocks + split-K -------
// grid (16, N_HEADS, B) = 512 blocks x 512 threads (8 waves).
// wave = (split s = wave>>2, rowgroup g = wave&3). Each block processes the
// Q-tile pair (31-bx, bx) sequentially. For each q-tile: split s handles key
// tiles kt ≡ s (mod 2) with its own single-buffered K/V LDS; lockstep barriers
// (J = ceil((qt+1)/2), one dummy iter max); (m,l,O) merged through LDS (reusing
// K/V area). Pair cost uniform: ceil((32-bx)/2)+ceil((bx+1)/2) = 17 iterations.
// 73728 B LDS -> 2 blocks/CU = 16 waves/CU = 4 waves/SIMD (was 2).
__global__ __launch_bounds__(512, 4) void attn_kernel(
    const unsigned short* __restrict__ qkv,   // (B*T, 3072) bf16 (for Q)
    const unsigned short* __restrict__ kst,   // [b][kvh][d8][t][8]
    const unsigned short* __restrict__ vst,   // [b][kvh][t8][d][8]
    unsigned short* __restrict__ aout)        // (B*T, D_MODEL) bf16
{
  __shared__ __align__(16) unsigned short sK[2][16 * 64 * 8];   // per split [d8][key][8]
  __shared__ __align__(16) unsigned short sV[2][8 * 128 * 8];   // per split [t8][d][8]
  __shared__ __align__(16) unsigned short sP[8][4 * 16 * 8];    // per wave, half-P

  const int tid  = threadIdx.x;
  const int wave = tid >> 6, lane = tid & 63;
  const int split = wave >> 2, g = wave & 3;
  const int quad = lane >> 4, l16 = lane & 15;
  const int head = blockIdx.y, b = blockIdx.z;
  const int kvh = head >> 2;
  const float cf = 0.08838834764831845f * 1.4426950408889634f;  // scale*log2e
  const float THR = 25.0f;  // defer-max threshold (raw S units)

  const unsigned short* kbase = kst + (size_t)((b * KV_HEADS + kvh) * 16) * 2048 * 8;
  const unsigned short* vbase = vst + (size_t)((b * KV_HEADS + kvh) * 256) * 128 * 8;
  unsigned short* sPw = sP[wave];

  // merge scratch overlays K/V LDS (only used after the kt loop, post-barrier)
  float* mrgO  = (float*)&sK[0][0];   // [g][row16][col128] f32 = 32 KB
  float* mrgML = (float*)&sV[0][0];   // [g][lane][r][{m,l}] f32 = 8 KB

  // per-wave stage of one K/V tile into split-s buffer (8 gload_lds / wave,
  // 4 waves of the split cover the 32 KB tile pair)
  #define STAGE_KV(sp, kb_) do {                                               \
    _Pragma("unroll")                                                          \
    for (int it_ = 0; it_ < 4; ++it_) {                                        \
      const int c_ = it_ * 4 + g;                                              \
      __builtin_amdgcn_global_load_lds(                                        \
          (gvoid_t*)(kbase + ((size_t)c_ * 2048 + (kb_)) * 8 + lane * 8),      \
          (svoid_t*)(&sK[sp][c_ * 512]), 16, 0, 0);                            \
    }                                                                          \
    const unsigned short* vt_ = vbase + (size_t)((kb_) >> 3) * 128 * 8;        \
    _Pragma("unroll")                                                          \
    for (int it_ = 0; it_ < 4; ++it_) {                                        \
      const int c_ = it_ * 4 + g;                                              \
      __builtin_amdgcn_global_load_lds(                                        \
          (gvoid_t*)(vt_ + c_ * 512 + lane * 8),                               \
          (svoid_t*)(&sV[sp][c_ * 512]), 16, 0, 0);                            \
    }                                                                          \
  } while (0)

  #pragma unroll 1
  for (int half = 0; half < 2; ++half) {
    const int qt = half ? blockIdx.x : (31 - blockIdx.x);
    const int q0 = qt * 64;

    // Q fragments (rowgroup g rows; both splits load the same rows)
    shortx8 qf[4];
    {
      const unsigned short* qp = qkv + (size_t)(b * T_SEQ + q0 + g * 16 + l16) * QKV_N
                                 + head * HEAD_DIM + quad * 8;
      #pragma unroll
      for (int ks = 0; ks < 4; ++ks)
        qf[ks] = *(const shortx8*)(qp + ks * 32);
    }

    float m_i[4], l_i[4];
    #pragma unroll
    for (int r = 0; r < 4; ++r) { m_i[r] = -__builtin_inff(); l_i[r] = 0.f; }
    floatx4 o_acc[8] = {};

    const int J = (qt >> 1) + 1;   // ceil((qt+1)/2)
    for (int j = 0; j < J; ++j) {
      const int kt = 2 * j + split;
      const bool act = (kt <= qt);

      __builtin_amdgcn_s_barrier();   // prev iteration's LDS reads complete
      if (act) STAGE_KV(split, kt * 64);
      asm volatile("s_waitcnt vmcnt(0)" ::: "memory");
      __builtin_amdgcn_s_barrier();   // tile visible to the split's 4 waves

      if (act) {
        // S = Q K^T for this wave's 16 rows x 64 keys
        floatx4 s[4] = {};
        __builtin_amdgcn_s_setprio(1);
        #pragma unroll
        for (int ks = 0; ks < 4; ++ks) {
          #pragma unroll
          for (int ct = 0; ct < 4; ++ct) {
            shortx8 kf = *(const shortx8*)&sK[split][((ks * 4 + quad) * 64 + ct * 16 + l16) * 8];
            s[ct] = mfma16(qf[ks], kf, s[ct]);
          }
        }
        __builtin_amdgcn_s_setprio(0);

        // causal mask only on the diagonal tile (wave-uniform branch)
        if (kt == qt) {
          const int qrow = q0 + g * 16 + quad * 4;
          const int kb = kt * 64;
          #pragma unroll
          for (int ct = 0; ct < 4; ++ct) {
            const int kcol = kb + ct * 16 + l16;
            #pragma unroll
            for (int r = 0; r < 4; ++r)
              if (kcol > qrow + r) s[ct][r] = -__builtin_inff();
          }
        }

        // tile max per row (16-lane reduce across l16)
        float mx[4];
        #pragma unroll
        for (int r = 0; r < 4; ++r) {
          float m = fmaxf(fmaxf(s[0][r], s[1][r]), fmaxf(s[2][r], s[3][r]));
          m = fmaxf(m, __shfl_xor(m, 1));
          m = fmaxf(m, __shfl_xor(m, 2));
          m = fmaxf(m, __shfl_xor(m, 4));
          m = fmaxf(m, __shfl_xor(m, 8));
          mx[r] = m;
        }

        // defer-max (T13)
        if (__ballot((mx[0] > m_i[0] + THR) || (mx[1] > m_i[1] + THR) ||
                     (mx[2] > m_i[2] + THR) || (mx[3] > m_i[3] + THR))) {
          float alpha_r[4];
          #pragma unroll
          for (int r = 0; r < 4; ++r) {
            const float newm = fmaxf(m_i[r], mx[r]);
            alpha_r[r] = exp2f((m_i[r] - newm) * cf);
            m_i[r] = newm;
            l_i[r] *= alpha_r[r];
          }
          #pragma unroll
          for (int nt = 0; nt < 8; ++nt)
            #pragma unroll
            for (int r = 0; r < 4; ++r) o_acc[nt][r] *= alpha_r[r];
        }

        // P = exp2((S - m)*cf); per-lane partial l
        #pragma unroll
        for (int r = 0; r < 4; ++r) {
          const float nmc = m_i[r] * cf;
          float p0 = exp2f(fmaf(s[0][r], cf, -nmc));
          float p1 = exp2f(fmaf(s[1][r], cf, -nmc));
          float p2 = exp2f(fmaf(s[2][r], cf, -nmc));
          float p3 = exp2f(fmaf(s[3][r], cf, -nmc));
          s[0][r] = p0; s[1][r] = p1; s[2][r] = p2; s[3][r] = p3;
          l_i[r] += (p0 + p1) + (p2 + p3);
        }

        // O += P V, two k-phases through a 1 KB per-wave sP
        #pragma unroll
        for (int c = 0; c < 2; ++c) {
          #pragma unroll
          for (int ctl = 0; ctl < 2; ++ctl) {
            const int ct = c * 2 + ctl;
            #pragma unroll
            for (int r = 0; r < 4; ++r)
              sPw[((ctl * 2 + (l16 >> 3)) * 16 + quad * 4 + r) * 8 + (l16 & 7)] =
                  f2bf_hw(s[ct][r]);
          }
          __asm__ __volatile__("s_waitcnt lgkmcnt(0)" ::: "memory");
          shortx8 pf = *(const shortx8*)&sPw[(quad * 16 + l16) * 8];
          __builtin_amdgcn_s_setprio(1);
          #pragma unroll
          for (int nt = 0; nt < 8; ++nt) {
            shortx8 vf = *(const shortx8*)&sV[split][((c * 4 + quad) * 128 + nt * 16 + l16) * 8];
            o_acc[nt] = mfma16(pf, vf, o_acc[nt]);
          }
          __builtin_amdgcn_s_setprio(0);
        }
      }
    }

    // ---- merge split partials, then epilogue (split0 finalizes) ----
    __builtin_amdgcn_s_barrier();   // all compute reads of K/V LDS done
    if (split == 1) {
      #pragma unroll
      for (int nt = 0; nt < 8; ++nt)
        #pragma unroll
        for (int r = 0; r < 4; ++r)
          mrgO[g * 2048 + (quad * 4 + r) * 128 + nt * 16 + l16] = o_acc[nt][r];
      #pragma unroll
      for (int r = 0; r < 4; ++r) {
        mrgML[(g * 64 + lane) * 8 + r * 2]     = m_i[r];
        mrgML[(g * 64 + lane) * 8 + r * 2 + 1] = l_i[r];
      }
    }
    asm volatile("s_waitcnt lgkmcnt(0)" ::: "memory");
    __builtin_amdgcn_s_barrier();   // partials visible

    if (split == 0) {
      float lm[4], a0[4], a1[4];
      #pragma unroll
      for (int r = 0; r < 4; ++r) {
        const float m1 = mrgML[(g * 64 + lane) * 8 + r * 2];
        const float l1 = mrgML[(g * 64 + lane) * 8 + r * 2 + 1];
        const float M = fmaxf(m_i[r], m1);
        a0[r] = exp2f((m_i[r] - M) * cf);
        a1[r] = exp2f((m1 - M) * cf);
        lm[r] = a0[r] * l_i[r] + a1[r] * l1;
      }
      #pragma unroll
      for (int nt = 0; nt < 8; ++nt)
        #pragma unroll
        for (int r = 0; r < 4; ++r)
          o_acc[nt][r] = a0[r] * o_acc[nt][r]
                       + a1[r] * mrgO[g * 2048 + (quad * 4 + r) * 128 + nt * 16 + l16];

      const int trow = q0 + g * 16 + quad * 4;
      #pragma unroll
      for (int r = 0; r < 4; ++r) {
        float l = lm[r];
        l += __shfl_xor(l, 1);
        l += __shfl_xor(l, 2);
        l += __shfl_xor(l, 4);
        l += __shfl_xor(l, 8);
        const float inv = 1.f / l;
        #pragma unroll
        for (int nt = 0; nt < 8; ++nt) {
          aout[(size_t)(b * T_SEQ + trow + r) * D_MODEL + head * HEAD_DIM + nt * 16 + l16] =
              f2bf_hw(o_acc[nt][r] * inv);
        }
      }
    }
  }
  #undef STAGE_KV
}

extern "C" void kernel_launch(void* const* d_in, const int* in_sizes, int n_in,
                              void* d_out, int out_size, void* d_ws, size_t ws_size,
                              hipStream_t stream) {
  const float* x      = (const float*)d_in[0];
  // d_in[1] = attn_mask (causal; unused)
  const float* qkv_w  = (const float*)d_in[2];
  const float* qkv_b  = (const float*)d_in[3];
  const float* proj_w = (const float*)d_in[4];
  const float* proj_b = (const float*)d_in[5];
  float* out = (float*)d_out;

  char* ws = (char*)d_ws;
  unsigned short* x_bf    = (unsigned short*)(ws);
  unsigned short* qkvw_t  = (unsigned short*)(ws + (size_t)16777216);
  unsigned short* projw_t = (unsigned short*)(ws + (size_t)29360128);
  unsigned short* qkvbuf  = (unsigned short*)(ws + (size_t)37748736);
  unsigned short* vstaged = (unsigned short*)(ws + (size_t)62914560);
  unsigned short* kstaged = qkvw_t;  // safe alias: qkvw_t dead after GEMM1
  unsigned short* attn_out = x_bf;   // safe alias: x_bf dead after GEMM1

  cvt_x<<<(ROWS * D_MODEL / 4 + 255) / 256, 256, 0, stream>>>(x, x_bf, ROWS * D_MODEL / 4);
  transpose_cvt<<<dim3(QKV_N / 32, D_MODEL / 32), dim3(32, 8), 0, stream>>>(qkv_w, qkvw_t, D_MODEL, QKV_N);
  transpose_cvt<<<dim3(D_MODEL / 32, D_MODEL / 32), dim3(32, 8), 0, stream>>>(proj_w, projw_t, D_MODEL, D_MODEL);
  gemm256<<<dim3(QKV_N / 256, ROWS / 256), 512, 0, stream>>>(
      x_bf, qkvw_t, qkv_b, (void*)qkvbuf, ROWS, QKV_N, D_MODEL, 1);
  build_kt<<<1024, 256, 0, stream>>>(qkvbuf, kstaged);
  build_vt<<<1024, 256, 0, stream>>>(qkvbuf, vstaged);
  attn_kernel<<<dim3(16, N_HEADS, BATCH), 512, 0, stream>>>(qkvbuf, kstaged, vstaged, attn_out);
  gemm256<<<dim3(D_MODEL / 256, ROWS / 256), 512, 0, stream>>>(
      attn_out, projw_t, proj_b, (void*)out, ROWS, D_MODEL, D_MODEL, 0);
}